// Round 1
// baseline (2357.944 us; speedup 1.0000x reference)
//
#include <hip/hip_runtime.h>

#define CC 256
#define NN 4096
#define BB 4
#define QT 64
#define JT 64
#define PAD 68   // floats per LDS row (16B-aligned, breaks 32-bank stride)

// ws layout (floats): M[256*256] @ 0 ; g[256] @ 65536 ; r2[B*N] @ 65792
#define WS_G  65536
#define WS_R2 (65536 + 256)

// K1: M[c][cp] = sum_o w1[o,c]*w2[o,cp] ; g[cp] = sum_o b1[o]*w2[o,cp]
__global__ void k_prep(const float* __restrict__ w1, const float* __restrict__ w2,
                       const float* __restrict__ b1, float* __restrict__ M,
                       float* __restrict__ g) {
    const int c  = blockIdx.x;
    const int cp = threadIdx.x;
    float acc = 0.f;
#pragma unroll 8
    for (int o = 0; o < CC; ++o)
        acc += w1[o * CC + c] * w2[o * CC + cp];
    M[c * CC + cp] = acc;
    if (c == 0) {
        float ga = 0.f;
        for (int o = 0; o < CC; ++o)
            ga += b1[o] * w2[o * CC + cp];
        g[cp] = ga;
    }
}

// K2: r2[b*N+j] = sum_c g[c] * x2[b,c,j]
__global__ void k_r2(const float* __restrict__ x2, const float* __restrict__ g,
                     float* __restrict__ r2) {
    const int jg = blockIdx.x * 256 + threadIdx.x;
    const int b  = jg >> 12;
    const int j  = jg & (NN - 1);
    const float* xp = x2 + (((size_t)(b * CC)) << 12) + j;
    float acc = 0.f;
#pragma unroll 8
    for (int c = 0; c < CC; ++c)
        acc += g[c] * xp[(size_t)c << 12];
    r2[jg] = acc;
}

// K3: fused (Q = M^T x1-tile) + flash attention with K=V=x2.
__launch_bounds__(256, 1)
__global__ void k_flash(const float* __restrict__ x1, const float* __restrict__ x2,
                        const float* __restrict__ M, const float* __restrict__ r2,
                        float* __restrict__ out) {
    extern __shared__ float lds[];
    float* Qs = lds;               // [256][PAD]  Q tile, cp-major
    float* Ks = Qs + CC * PAD;     // [256][PAD]  K/V tile (also x1 staging)
    float* Ps = Ks + CC * PAD;     // [QT][PAD]   softmax probabilities
    float* sc = Ps + QT * PAD;     // [QT] rescale factors
    float* li = sc + QT;           // [QT] 1/l

    const int tid = threadIdx.x;
    const int b   = blockIdx.x >> 6;
    const int i0  = (blockIdx.x & 63) << 6;

    const float* x1b = x1 + (((size_t)(b * CC)) << 12);
    const float* x2b = x2 + (((size_t)(b * CC)) << 12);

    // ---- phase 0a: stage x1[:, i0:i0+64] into Ks ----
#pragma unroll
    for (int rep = 0; rep < 16; ++rep) {
        int idx = (rep << 8) + tid;
        int c = idx >> 4, f4 = (idx & 15) << 2;
        *(float4*)&Ks[c * PAD + f4] =
            *(const float4*)(x1b + (((size_t)c) << 12) + i0 + f4);
    }
    __syncthreads();

    // ---- phase 0b: Qs[cp][i] = sum_c M[c][cp] * x1s[c][i] ----
    {
        const int tc = tid & 63;   // cp/4
        const int tq = tid >> 6;   // i/16
        float acc[4][16];
#pragma unroll
        for (int r = 0; r < 4; ++r)
#pragma unroll
            for (int e = 0; e < 16; ++e) acc[r][e] = 0.f;
#pragma unroll 4
        for (int c = 0; c < CC; ++c) {
            float4 mv = *(const float4*)(M + c * CC + (tc << 2));
#pragma unroll
            for (int k = 0; k < 4; ++k) {
                float4 xv = *(const float4*)&Ks[c * PAD + (tq << 4) + (k << 2)];
                acc[0][4*k+0] += mv.x * xv.x; acc[0][4*k+1] += mv.x * xv.y;
                acc[0][4*k+2] += mv.x * xv.z; acc[0][4*k+3] += mv.x * xv.w;
                acc[1][4*k+0] += mv.y * xv.x; acc[1][4*k+1] += mv.y * xv.y;
                acc[1][4*k+2] += mv.y * xv.z; acc[1][4*k+3] += mv.y * xv.w;
                acc[2][4*k+0] += mv.z * xv.x; acc[2][4*k+1] += mv.z * xv.y;
                acc[2][4*k+2] += mv.z * xv.z; acc[2][4*k+3] += mv.z * xv.w;
                acc[3][4*k+0] += mv.w * xv.x; acc[3][4*k+1] += mv.w * xv.y;
                acc[3][4*k+2] += mv.w * xv.z; acc[3][4*k+3] += mv.w * xv.w;
            }
        }
#pragma unroll
        for (int r = 0; r < 4; ++r)
#pragma unroll
            for (int k = 0; k < 4; ++k) {
                float4 v = make_float4(acc[r][4*k+0], acc[r][4*k+1],
                                       acc[r][4*k+2], acc[r][4*k+3]);
                *(float4*)&Qs[((tc << 2) + r) * PAD + (tq << 4) + (k << 2)] = v;
            }
    }

    const int tx = tid & 15;   // S: j/4  | PV: channel lane
    const int ty = tid >> 4;   // S: i/4  | PV: i/4

    float m_run[4], l_run[4];
#pragma unroll
    for (int r = 0; r < 4; ++r) { m_run[r] = -1e30f; l_run[r] = 0.f; }
    float accv[16][4];
#pragma unroll
    for (int ci = 0; ci < 16; ++ci)
#pragma unroll
        for (int u = 0; u < 4; ++u) accv[ci][u] = 0.f;

    for (int jt = 0; jt < 64; ++jt) {
        const int j0 = jt << 6;
        __syncthreads();   // prev tile's PV (and phase-0b reads) done
#pragma unroll
        for (int rep = 0; rep < 16; ++rep) {
            int idx = (rep << 8) + tid;
            int c = idx >> 4, f4 = (idx & 15) << 2;
            *(float4*)&Ks[c * PAD + f4] =
                *(const float4*)(x2b + (((size_t)c) << 12) + j0 + f4);
        }
        __syncthreads();   // K/V tile ready

        // ---- S = Q^T K ----
        float S[4][4];
#pragma unroll
        for (int r = 0; r < 4; ++r)
#pragma unroll
            for (int s = 0; s < 4; ++s) S[r][s] = 0.f;
#pragma unroll 4
        for (int c = 0; c < CC; ++c) {
            float4 qv = *(const float4*)&Qs[c * PAD + (ty << 2)];
            float4 kv = *(const float4*)&Ks[c * PAD + (tx << 2)];
            S[0][0] += qv.x*kv.x; S[0][1] += qv.x*kv.y; S[0][2] += qv.x*kv.z; S[0][3] += qv.x*kv.w;
            S[1][0] += qv.y*kv.x; S[1][1] += qv.y*kv.y; S[1][2] += qv.y*kv.z; S[1][3] += qv.y*kv.w;
            S[2][0] += qv.z*kv.x; S[2][1] += qv.z*kv.y; S[2][2] += qv.z*kv.z; S[2][3] += qv.z*kv.w;
            S[3][0] += qv.w*kv.x; S[3][1] += qv.w*kv.y; S[3][2] += qv.w*kv.z; S[3][3] += qv.w*kv.w;
        }
        {
            float4 r2v = *(const float4*)(r2 + (b << 12) + j0 + (tx << 2));
#pragma unroll
            for (int r = 0; r < 4; ++r) {
                S[r][0] += r2v.x; S[r][1] += r2v.y; S[r][2] += r2v.z; S[r][3] += r2v.w;
            }
        }

        // ---- online softmax (row i = 4*ty + r spread over 16 lanes tx) ----
#pragma unroll
        for (int r = 0; r < 4; ++r) {
            float mx = fmaxf(fmaxf(S[r][0], S[r][1]), fmaxf(S[r][2], S[r][3]));
#pragma unroll
            for (int d = 1; d < 16; d <<= 1) mx = fmaxf(mx, __shfl_xor(mx, d));
            float mn  = fmaxf(m_run[r], mx);
            float scl = expf(m_run[r] - mn);
            float p0 = expf(S[r][0] - mn), p1 = expf(S[r][1] - mn);
            float p2 = expf(S[r][2] - mn), p3 = expf(S[r][3] - mn);
            float rs = p0 + p1 + p2 + p3;
#pragma unroll
            for (int d = 1; d < 16; d <<= 1) rs += __shfl_xor(rs, d);
            l_run[r] = l_run[r] * scl + rs;
            m_run[r] = mn;
            *(float4*)&Ps[((ty << 2) + r) * PAD + (tx << 2)] = make_float4(p0, p1, p2, p3);
            if (tx == 0) sc[(ty << 2) + r] = scl;
        }
        __syncthreads();   // Ps, sc ready

        // ---- PV: out[c, i] += sum_j V[c,j] * P[i,j] ----
        float s_u[4];
#pragma unroll
        for (int u = 0; u < 4; ++u) s_u[u] = sc[(ty << 2) + u];
#pragma unroll
        for (int ci = 0; ci < 16; ++ci)
#pragma unroll
            for (int u = 0; u < 4; ++u) accv[ci][u] *= s_u[u];

#pragma unroll 2
        for (int jc = 0; jc < 16; ++jc) {
            float4 pu[4];
#pragma unroll
            for (int u = 0; u < 4; ++u)
                pu[u] = *(const float4*)&Ps[((ty << 2) + u) * PAD + (jc << 2)];
#pragma unroll
            for (int ci = 0; ci < 16; ++ci) {
                float4 vv = *(const float4*)&Ks[(tx + (ci << 4)) * PAD + (jc << 2)];
#pragma unroll
                for (int u = 0; u < 4; ++u)
                    accv[ci][u] += vv.x * pu[u].x + vv.y * pu[u].y +
                                   vv.z * pu[u].z + vv.w * pu[u].w;
            }
        }
    }

    // ---- finalize ----
    if (tx == 0) {
#pragma unroll
        for (int r = 0; r < 4; ++r) li[(ty << 2) + r] = 1.f / l_run[r];
    }
    __syncthreads();
    float lv[4];
#pragma unroll
    for (int u = 0; u < 4; ++u) lv[u] = li[(ty << 2) + u];
    float* outb = out + (((size_t)(b * CC)) << 12) + i0;
#pragma unroll
    for (int ci = 0; ci < 16; ++ci) {
        size_t row = ((size_t)(tx + (ci << 4))) << 12;
        float4 ov = make_float4(accv[ci][0] * lv[0], accv[ci][1] * lv[1],
                                accv[ci][2] * lv[2], accv[ci][3] * lv[3]);
        *(float4*)(outb + row + (ty << 2)) = ov;
    }
}

extern "C" void kernel_launch(void* const* d_in, const int* in_sizes, int n_in,
                              void* d_out, int out_size, void* d_ws, size_t ws_size,
                              hipStream_t stream) {
    const float* x1 = (const float*)d_in[0];
    const float* x2 = (const float*)d_in[1];
    const float* w1 = (const float*)d_in[2];
    const float* b1 = (const float*)d_in[3];
    const float* w2 = (const float*)d_in[4];
    // b2 (d_in[5]) only contributes row-constant terms -> cancels in softmax.
    float* M  = (float*)d_ws;
    float* g  = M + WS_G  - 65536 + 65536;         // = M + 65536
    float* r2 = M + WS_R2;
    g = M + WS_G;

    float* outp = (float*)d_out;

    const int LDS_BYTES = (2 * CC * PAD + QT * PAD + 2 * QT) * (int)sizeof(float); // 157184
    (void)hipFuncSetAttribute((const void*)k_flash,
                              hipFuncAttributeMaxDynamicSharedMemorySize, LDS_BYTES);

    k_prep<<<CC, 256, 0, stream>>>(w1, w2, b1, M, g);
    k_r2<<<BB * NN / 256, 256, 0, stream>>>(x2, g, r2);
    k_flash<<<BB * (NN / QT), 256, LDS_BYTES, stream>>>(x1, x2, M, r2, outp);
    (void)in_sizes; (void)n_in; (void)out_size; (void)ws_size;
}

// Round 4
// 627.420 us; speedup vs baseline: 3.7582x; 3.7582x over previous
//
#include <hip/hip_runtime.h>

typedef _Float16 f16;
typedef _Float16 f16x8 __attribute__((ext_vector_type(8)));
typedef _Float16 f16x4 __attribute__((ext_vector_type(4)));
typedef float    f32x4 __attribute__((ext_vector_type(4)));
typedef unsigned int u32;
typedef u32 u32x2 __attribute__((ext_vector_type(2)));
typedef u32 u32x4 __attribute__((ext_vector_type(4)));
typedef unsigned short ush;

#define CC 256
#define NN 4096
#define BB 4
#define RS 264          // row stride (halves) for K/Q tiles: 2-way-free b128 reads
#define RSV 40          // row stride (halves) for V tile
#define RSC 17          // row stride (f32) for combine buffer

union Frag8 { u32x4 u4; f16x8 f; };
union Frag4 { u32x2 u2; f16x4 f; };

static __device__ __forceinline__ u32 pkrtz(float a, float b) {
  auto t = __builtin_amdgcn_cvt_pkrtz(a, b);
  return __builtin_bit_cast(u32, t);
}
static __device__ __forceinline__ float h2fu(u32 u) {
  f16 h = __builtin_bit_cast(f16, (ush)(u & 0xffffu));
  return (float)h;
}

#define MFMA32(A, B, C) __builtin_amdgcn_mfma_f32_16x16x32_f16((A), (B), (C), 0, 0, 0)
#define MFMA16(A, B, C) __builtin_amdgcn_mfma_f32_16x16x16f16((A), (B), (C), 0, 0, 0)

// K1: M[c][cp] = sum_o w1[o,c]*w2[o,cp] (f32) ; g[cp] = sum_o b1[o]*w2[o,cp]
__global__ void k_prep(const float* __restrict__ w1, const float* __restrict__ w2,
                       const float* __restrict__ b1, float* __restrict__ M,
                       float* __restrict__ g) {
  const int c  = blockIdx.x;
  const int cp = threadIdx.x;
  float acc = 0.f;
#pragma unroll 8
  for (int o = 0; o < CC; ++o)
    acc += w1[o * CC + c] * w2[o * CC + cp];
  M[c * CC + cp] = acc;
  if (c == 0) {
    float ga = 0.f;
    for (int o = 0; o < CC; ++o)
      ga += b1[o] * w2[o * CC + cp];
    g[cp] = ga;
  }
}

// K2: r2[b*N+j] = sum_c g[c] * x2[b,c,j]
__global__ void k_r2(const float* __restrict__ x2, const float* __restrict__ g,
                     float* __restrict__ r2) {
  const int jg = blockIdx.x * 256 + threadIdx.x;
  const int b  = jg >> 12;
  const int j  = jg & (NN - 1);
  const float* xp = x2 + (((size_t)(b * CC)) << 12) + j;
  float acc = 0.f;
#pragma unroll 8
  for (int c = 0; c < CC; ++c)
    acc += g[c] * xp[(size_t)c << 12];
  r2[jg] = acc;
}

// K3: Q-prep (VALU f32) + flash attention (MFMA: 3-pass fp16 S, fp16 PV)
// LDS regions (bytes): A = [0, 40960), B = [40960, 74752)
//  A: x1f32[256][40]f32 -> Qhi[32][264]h + Qlo[32][264]h -> Khi+Klo -> Cmb[2][256][17]f32
//  B: Qf32[32][264]f32  -> V[256][40]h ; Msm/Lsm at merge
__launch_bounds__(256, 2)
__global__ void k_attn(const float* __restrict__ x1, const float* __restrict__ x2,
                       const float* __restrict__ M, const float* __restrict__ r2,
                       float* __restrict__ out) {
  extern __shared__ ush lds[];
  ush*   A_h   = lds;                      // region A as halves
  float* A_f   = (float*)lds;              // region A as f32
  ush*   B_h   = lds + 20480;              // region B as halves (byte 40960)
  float* B_f   = (float*)(lds + 20480);    // region B as f32

  const int tid  = threadIdx.x;
  const int lane = tid & 63;
  const int w    = tid >> 6;
  const int p    = w >> 1;     // i-group (16 i each)
  const int h    = w & 1;      // j-group (16 j each)
  const int g    = lane >> 4;
  const int lq   = lane & 15;

  int bid = (int)blockIdx.x;
  bid = (bid & 7) * 64 + (bid >> 3);       // bijective XCD swizzle (512 = 8*64)
  const int b  = bid >> 7;
  const int i0 = (bid & 127) << 5;

  const float* x1b = x1 + ((size_t)b << 20);
  const float* x2b = x2 + ((size_t)b << 20);

  // ---- phase A: stage x1[:, i0:i0+32] as f32 into A: x1f32[c][40] ----
  {
    const int jf = tid & 7;
    const int c0 = tid >> 3;
#pragma unroll
    for (int m = 0; m < 8; ++m) {
      int c = c0 + (m << 5);
      float4 v = *(const float4*)(x1b + ((size_t)c << 12) + i0 + (jf << 2));
      *(float4*)(A_f + c * RSV + (jf << 2)) = v;
    }
  }
  __syncthreads();

  // ---- phase B: Q[i][cp] = sum_c M[c][cp] * x1f32[c][i]  (VALU f32) ----
  {
    const int tc = tid & 63;   // cp quad: cp = 4*tc
    const int tq = tid >> 6;   // i octet: i = 8*tq
    float acc[4][8];
#pragma unroll
    for (int q = 0; q < 4; ++q)
#pragma unroll
      for (int e = 0; e < 8; ++e) acc[q][e] = 0.f;
#pragma unroll 4
    for (int c = 0; c < CC; ++c) {
      float4 mv = *(const float4*)(M + c * CC + (tc << 2));
      float4 xa = *(const float4*)(A_f + c * RSV + (tq << 3));
      float4 xb = *(const float4*)(A_f + c * RSV + (tq << 3) + 4);
      float xs[8] = {xa.x, xa.y, xa.z, xa.w, xb.x, xb.y, xb.z, xb.w};
#pragma unroll
      for (int e = 0; e < 8; ++e) {
        acc[0][e] += mv.x * xs[e];
        acc[1][e] += mv.y * xs[e];
        acc[2][e] += mv.z * xs[e];
        acc[3][e] += mv.w * xs[e];
      }
    }
#pragma unroll
    for (int e = 0; e < 8; ++e) {
      float4 v = make_float4(acc[0][e], acc[1][e], acc[2][e], acc[3][e]);
      *(float4*)(B_f + ((tq << 3) + e) * RS + (tc << 2)) = v;   // Qf32[i][cp]
    }
  }
  __syncthreads();

  // ---- phase C: repack Qf32 -> Qhi/Qlo [32][264] halves in region A ----
  {
    ush* Qhi = A_h;
    ush* Qlo = A_h + 32 * RS;
    const int i  = tid >> 3;
    const int ch = tid & 7;            // cp chunk of 32
    const float* src = B_f + i * RS + (ch << 5);
    u32 hi[16], lo[16];
#pragma unroll
    for (int k = 0; k < 8; ++k) {
      float4 a = *(const float4*)(src + (k << 2));
      u32 h0 = pkrtz(a.x, a.y), h1 = pkrtz(a.z, a.w);
      hi[2 * k]     = h0;
      hi[2 * k + 1] = h1;
      float l0 = a.x - h2fu(h0), l1 = a.y - h2fu(h0 >> 16);
      float l2 = a.z - h2fu(h1), l3 = a.w - h2fu(h1 >> 16);
      lo[2 * k]     = pkrtz(l0, l1);
      lo[2 * k + 1] = pkrtz(l2, l3);
    }
#pragma unroll
    for (int m = 0; m < 4; ++m) {
      u32x4 vh; vh.x = hi[4*m]; vh.y = hi[4*m+1]; vh.z = hi[4*m+2]; vh.w = hi[4*m+3];
      u32x4 vl; vl.x = lo[4*m]; vl.y = lo[4*m+1]; vl.z = lo[4*m+2]; vl.w = lo[4*m+3];
      *(u32x4*)(Qhi + i * RS + (ch << 5) + (m << 3)) = vh;
      *(u32x4*)(Qlo + i * RS + (ch << 5) + (m << 3)) = vl;
    }
  }
  __syncthreads();

  // ---- phase D: preload this wave's Q B-fragments (loop-invariant) ----
  Frag8 QBh[8], QBl[8];
  {
    const ush* Qhi = A_h;
    const ush* Qlo = A_h + 32 * RS;
    const int qrow = ((p << 4) + lq) * RS;
#pragma unroll
    for (int cs = 0; cs < 8; ++cs) {
      QBh[cs].u4 = *(const u32x4*)(Qhi + qrow + (cs << 5) + (g << 3));
      QBl[cs].u4 = *(const u32x4*)(Qlo + qrow + (cs << 5) + (g << 3));
    }
  }

  // ---- main flash loop: 128 j-tiles of 32 ----
  ush* Khi = A_h;
  ush* Klo = A_h + 32 * RS;
  ush* V   = B_h;

  f32x4 vacc[16];
#pragma unroll
  for (int ct = 0; ct < 16; ++ct) vacc[ct] = (f32x4){0.f, 0.f, 0.f, 0.f};
  float m_run = -3.0e38f, l_run = 0.f;

  const int jj  = tid & 31;         // K-staging j
  const int cq4 = (tid >> 5) << 2;  // K-staging c-quad base
  const int jf  = tid & 7;          // V-staging j-quad
  const int cV  = tid >> 3;         // V-staging c
  const int arow0 = ((h << 4) + lq) * RS + (g << 3);
  const int vcol  = (h << 4) + (g << 2);
  const float* r2p = r2 + (b << 12) + (h << 4) + (g << 2);

  for (int t = 0; t < 128; ++t) {
    const int j0 = t << 5;
    __syncthreads();
    // -- stage K transposed: Khi/Klo[j][c], c-strided coalesced dword loads --
#pragma unroll
    for (int m = 0; m < 8; ++m) {
      int c = cq4 + (m << 5);
      const float* xp = x2b + ((size_t)c << 12) + j0 + jj;
      float v0 = xp[0];
      float v1 = xp[4096];
      float v2 = xp[8192];
      float v3 = xp[12288];
      u32 h0 = pkrtz(v0, v1), h1 = pkrtz(v2, v3);
      float l0 = v0 - h2fu(h0), l1 = v1 - h2fu(h0 >> 16);
      float l2 = v2 - h2fu(h1), l3 = v3 - h2fu(h1 >> 16);
      u32x2 hw; hw.x = h0; hw.y = h1;
      u32x2 lw; lw.x = pkrtz(l0, l1); lw.y = pkrtz(l2, l3);
      *(u32x2*)(Khi + jj * RS + c) = hw;
      *(u32x2*)(Klo + jj * RS + c) = lw;
    }
    // -- stage V natural: V[c][j] halves --
#pragma unroll
    for (int m = 0; m < 8; ++m) {
      int c = cV + (m << 5);
      float4 v = *(const float4*)(x2b + ((size_t)c << 12) + j0 + (jf << 2));
      u32x2 hw; hw.x = pkrtz(v.x, v.y); hw.y = pkrtz(v.z, v.w);
      *(u32x2*)(V + c * RSV + (jf << 2)) = hw;
    }
    __syncthreads();

    // -- S^T = K·Q (3-pass): D[j][i], lane: j=16h+4g+r, i=16p+lq --
    f32x4 aS = {0.f, 0.f, 0.f, 0.f};
#pragma unroll
    for (int cs = 0; cs < 8; ++cs) {
      Frag8 Ah, Al;
      Ah.u4 = *(const u32x4*)(Khi + arow0 + (cs << 5));
      Al.u4 = *(const u32x4*)(Klo + arow0 + (cs << 5));
      aS = MFMA32(Ah.f, QBh[cs].f, aS);
      aS = MFMA32(Ah.f, QBl[cs].f, aS);
      aS = MFMA32(Al.f, QBh[cs].f, aS);
    }

    // -- online softmax over this wave's 16 j --
    float4 r2v = *(const float4*)(r2p + j0);
    float s0 = aS[0] + r2v.x, s1 = aS[1] + r2v.y;
    float s2 = aS[2] + r2v.z, s3 = aS[3] + r2v.w;
    float mx = fmaxf(fmaxf(s0, s1), fmaxf(s2, s3));
    mx = fmaxf(mx, __shfl_xor(mx, 16));
    mx = fmaxf(mx, __shfl_xor(mx, 32));
    float mn  = fmaxf(m_run, mx);
    float scl = __expf(m_run - mn);
    float p0 = __expf(s0 - mn), p1 = __expf(s1 - mn);
    float p2 = __expf(s2 - mn), p3 = __expf(s3 - mn);
    float rs = p0 + p1 + p2 + p3;
    rs += __shfl_xor(rs, 16);
    rs += __shfl_xor(rs, 32);
    l_run = l_run * scl + rs;
    m_run = mn;

    // P fragment is lane-local: B[k=4g+e][col=lq] = P[j''=4g+e][i]
    Frag4 Pf;
    Pf.u2.x = pkrtz(p0, p1);
    Pf.u2.y = pkrtz(p2, p3);

    // -- PV: vacc[c][i] += V·P, K=16 over this wave's 16 j --
#pragma unroll
    for (int ct = 0; ct < 16; ++ct) {
      vacc[ct][0] *= scl; vacc[ct][1] *= scl;
      vacc[ct][2] *= scl; vacc[ct][3] *= scl;
    }
#pragma unroll
    for (int ct = 0; ct < 16; ++ct) {
      Frag4 Vf;
      Vf.u2 = *(const u32x2*)(V + (lq + (ct << 4)) * RSV + vcol);
      vacc[ct] = MFMA16(Vf.f, Pf.f, vacc[ct]);
    }
  }

  // ---- merge j-halves (h=0 & h=1), normalize, store ----
  __syncthreads();
  float* Msm = B_f;          // region B (V dead)
  float* Lsm = B_f + 64;
  if (g == 0) {
    Msm[p * 32 + h * 16 + lq] = m_run;
    Lsm[p * 32 + h * 16 + lq] = l_run;
  }
  __syncthreads();
  float mo  = Msm[p * 32 + (1 - h) * 16 + lq];
  float lo2 = Lsm[p * 32 + (1 - h) * 16 + lq];
  float mt    = fmaxf(m_run, mo);
  float aSelf = __expf(m_run - mt);
  float l_tot = l_run * aSelf + lo2 * __expf(mo - mt);

  float* Cmb = A_f;          // region A (K dead): [2][256][17]
  if (h == 0) {
    float* cb_ = Cmb + p * (CC * RSC);
#pragma unroll
    for (int ct = 0; ct < 16; ++ct)
#pragma unroll
      for (int r = 0; r < 4; ++r)
        cb_[((ct << 4) + (g << 2) + r) * RSC + lq] = vacc[ct][r] * aSelf;
  }
  __syncthreads();
  if (h == 1) {
    const float* cb_ = Cmb + p * (CC * RSC);
    float inv = 1.f / l_tot;
    float* ob = out + ((size_t)b << 20) + i0 + (p << 4) + lq;
#pragma unroll
    for (int ct = 0; ct < 16; ++ct)
#pragma unroll
      for (int r = 0; r < 4; ++r) {
        int c = (ct << 4) + (g << 2) + r;
        ob[(size_t)c << 12] = (vacc[ct][r] * aSelf + cb_[c * RSC + lq]) * inv;
      }
  }
}

extern "C" void kernel_launch(void* const* d_in, const int* in_sizes, int n_in,
                              void* d_out, int out_size, void* d_ws, size_t ws_size,
                              hipStream_t stream) {
  const float* x1 = (const float*)d_in[0];
  const float* x2 = (const float*)d_in[1];
  const float* w1 = (const float*)d_in[2];
  const float* b1 = (const float*)d_in[3];
  const float* w2 = (const float*)d_in[4];
  // b2 (d_in[5]) contributes only row-constant energy terms -> cancels in softmax.

  float* M  = (float*)d_ws;          // [256][256] f32
  float* g  = M + 65536;
  float* r2 = g + 256;
  float* outp = (float*)d_out;

  const int LDS_BYTES = 74752;
  (void)hipFuncSetAttribute((const void*)k_attn,
                            hipFuncAttributeMaxDynamicSharedMemorySize, LDS_BYTES);

  k_prep<<<CC, 256, 0, stream>>>(w1, w2, b1, M, g);
  k_r2<<<BB * NN / 256, 256, 0, stream>>>(x2, g, r2);
  k_attn<<<BB * (NN / 32), 256, LDS_BYTES, stream>>>(x1, x2, M, r2, outp);
  (void)in_sizes; (void)n_in; (void)out_size; (void)ws_size;
}